// Round 1
// baseline (397.394 us; speedup 1.0000x reference)
//
#include <hip/hip_runtime.h>
#include <hip/hip_bf16.h>

#define RADIUS_F 1.3f
#define NSAMP 767
#define STEPF 0.01015625f   // RADIUS*2/COARSE/FINE/2
#define BATCH 1024

__launch_bounds__(256, 2)
__global__ void plenoxels_fwd(const float* __restrict__ rays_o,
                              const float* __restrict__ rays_d,
                              const float* __restrict__ grid,
                              const float* __restrict__ atoms,
                              float* __restrict__ out)
{
    // LDS: 57344 + 17408 + 1536 + 4608 = 80896 B -> 2 blocks/CU on gfx950 (160 KB)
    __shared__ float atomsL[8 * 64 * 28];
    __shared__ float coefL[2][32][68];      // stride 68: bank offset 4/group -> conflict-free bcast
    __shared__ __hip_bfloat16 alphaL[768];
    __shared__ __hip_bfloat16 rgbL[768 * 3];

    const int tid = threadIdx.x;
    const int ray = blockIdx.x;

    // ---- stage atoms into LDS (float4, coalesced) ----
    {
        const float4* a4 = (const float4*)atoms;
        float4* l4 = (float4*)atomsL;
        for (int i = tid; i < (8 * 64 * 28) / 4; i += 256) l4[i] = a4[i];
    }

    // ---- per-ray constants (computed redundantly per thread) ----
    const float ox = rays_o[ray * 3 + 0], oy = rays_o[ray * 3 + 1], oz = rays_o[ray * 3 + 2];
    const float dx = rays_d[ray * 3 + 0], dy = rays_d[ray * 3 + 1], dz = rays_d[ray * 3 + 2];

    float start;
    {
        float a0 = (RADIUS_F - ox) / dx, b0 = (-RADIUS_F - ox) / dx;
        float a1 = (RADIUS_F - oy) / dy, b1 = (-RADIUS_F - oy) / dy;
        float a2 = (RADIUS_F - oz) / dz, b2 = (-RADIUS_F - oz) / dz;
        start = fmaxf(fminf(a0, b0), fmaxf(fminf(a1, b1), fminf(a2, b2)));
    }
    const float dnorm = sqrtf(dx * dx + dy * dy + dz * dz);
    const float dist = STEPF * dnorm;

    float shm[9];
    {
        float inv = 1.0f / dnorm;
        float nx = dx * inv, ny = dy * inv, nz = dz * inv;
        shm[0] = 0.28209479177387814f;
        shm[1] = -0.4886025119029199f * ny;
        shm[2] = 0.4886025119029199f * nz;
        shm[3] = -0.4886025119029199f * nx;
        shm[4] = 1.0925484305920792f * nx * ny;
        shm[5] = -1.0925484305920792f * ny * nz;
        shm[6] = 0.31539156525252005f * (2.f * nz * nz - nx * nx - ny * ny);
        shm[7] = -1.0925484305920792f * nx * nz;
        shm[8] = 0.5462742152960396f * (nx * nx - ny * ny);
    }

    const int g   = tid >> 3;            // group 0..31 (one group = one sample slot)
    const int dq  = tid & 7;             // d-quad lane 0..7 (7 active for 28 dims)
    const int dqe = (dq < 7) ? dq : 6;

    // per-lane SH weights for the 4 data dims this lane owns (no dynamic indexing)
    float wr[4], wg[4], wb[4];
    #pragma unroll
    for (int j = 0; j < 4; ++j) {
        int d = dqe * 4 + j;
        int c = d / 9;
        int k = d - 9 * c;
        float v = 0.f;
        #pragma unroll
        for (int q = 0; q < 9; ++q) v = (k == q) ? shm[q] : v;
        bool act = (dq < 7);
        wr[j] = (act && c == 0) ? v : 0.f;
        wg[j] = (act && c == 1) ? v : 0.f;
        wb[j] = (act && c == 2) ? v : 0.f;
    }

    __syncthreads();

    float* out_rgb   = out;
    float* out_alpha = out + BATCH * 3;
    float* out_depth = out + BATCH * 3 + BATCH * NSAMP;

    const float4* g4 = (const float4*)grid;
    const float4* at4 = (const float4*)atomsL;

    // geometry + trilinear fine weights for one sample
    auto geom = [&](int s, float W[8], int& clin) -> int {
        float tr = start + (float)s * STEPF;
        float px = ox + tr * dx, py = oy + tr * dy, pz = oz + tr * dz;
        int mask = (px > -RADIUS_F) & (px < RADIUS_F) &
                   (py > -RADIUS_F) & (py < RADIUS_F) &
                   (pz > -RADIUS_F) & (pz < RADIUS_F);
        const float sc = 1.0f / (2.0f * RADIUS_F);
        float qx = fminf(fmaxf((px + RADIUS_F) * sc, 0.f), 1.0f - 1e-6f);
        float qy = fminf(fmaxf((py + RADIUS_F) * sc, 0.f), 1.0f - 1e-6f);
        float qz = fminf(fmaxf((pz + RADIUS_F) * sc, 0.f), 1.0f - 1e-6f);
        float pcx = qx * 64.f, pcy = qy * 64.f, pcz = qz * 64.f;
        float cx = fminf(floorf(pcx), 63.f);
        float cy = fminf(floorf(pcy), 63.f);
        float cz = fminf(floorf(pcz), 63.f);
        float lx = pcx - cx, ly = pcy - cy, lz = pcz - cz;
        clin = (((int)cx * 64) + (int)cy) * 64 + (int)cz;
        float xw0, xw1, yw0, yw1, zw0, zw1;
        {
            float u = lx * 2.f - 0.5f, fF = floorf(u), t = u - fF;
            xw0 = (fF < 0.f) ? 1.f : ((fF > 0.f) ? 0.f : 1.f - t);
            xw1 = (fF < 0.f) ? 0.f : ((fF > 0.f) ? 1.f : t);
        }
        {
            float u = ly * 2.f - 0.5f, fF = floorf(u), t = u - fF;
            yw0 = (fF < 0.f) ? 1.f : ((fF > 0.f) ? 0.f : 1.f - t);
            yw1 = (fF < 0.f) ? 0.f : ((fF > 0.f) ? 1.f : t);
        }
        {
            float u = lz * 2.f - 0.5f, fF = floorf(u), t = u - fF;
            zw0 = (fF < 0.f) ? 1.f : ((fF > 0.f) ? 0.f : 1.f - t);
            zw1 = (fF < 0.f) ? 0.f : ((fF > 0.f) ? 1.f : t);
        }
        W[0] = xw0 * yw0 * zw0; W[1] = xw0 * yw0 * zw1;
        W[2] = xw0 * yw1 * zw0; W[3] = xw0 * yw1 * zw1;
        W[4] = xw1 * yw0 * zw0; W[5] = xw1 * yw0 * zw1;
        W[6] = xw1 * yw1 * zw0; W[7] = xw1 * yw1 * zw1;
        return mask;
    };

    // SH-dot + sigma epilogue for one sample (group-wide shuffle reduce, dq0 writes)
    auto emit = [&](int s, float4 dv, int mask) {
        float pr = wr[0]*dv.x + wr[1]*dv.y + wr[2]*dv.z + wr[3]*dv.w;
        float pg = wg[0]*dv.x + wg[1]*dv.y + wg[2]*dv.z + wg[3]*dv.w;
        float pb = wb[0]*dv.x + wb[1]*dv.y + wb[2]*dv.z + wb[3]*dv.w;
        float sg = (dq == 6) ? dv.w : 0.f;   // data[27]
        #pragma unroll
        for (int m = 1; m < 8; m <<= 1) {
            pr += __shfl_xor(pr, m, 8);
            pg += __shfl_xor(pg, m, 8);
            pb += __shfl_xor(pb, m, 8);
            sg += __shfl_xor(sg, m, 8);
        }
        if (dq == 0 && s < NSAMP) {
            float sigma = mask ? fmaxf(sg, 0.f) : 0.f;
            float alpha = 1.f - __expf(-sigma * dist);
            out_alpha[ray * NSAMP + s] = alpha;          // exact fp32 output
            alphaL[s] = __float2bfloat16(alpha);
            float rr = mask ? (1.f / (1.f + __expf(-pr))) : 0.5f;
            float gg = mask ? (1.f / (1.f + __expf(-pg))) : 0.5f;
            float bb = mask ? (1.f / (1.f + __expf(-pb))) : 0.5f;
            rgbL[s * 3 + 0] = __float2bfloat16(rr);
            rgbL[s * 3 + 1] = __float2bfloat16(gg);
            rgbL[s * 3 + 2] = __float2bfloat16(bb);
        }
    };

    // ---- main loop: 12 sweeps x 64 samples (2 samples per group per sweep) ----
    for (int it = 0; it < 12; ++it) {
        const int s0 = it * 64 + g;
        const int s1 = s0 + 32;

        float W0[8], W1[8];
        int clin0, clin1;
        int m0 = geom(s0, W0, clin0);
        int m1 = geom(s1, W1, clin1);

        // stage coeff rows for both samples (64 floats each, 8 lanes x 2 float4)
        {
            float4 c00 = g4[clin0 * 16 + dq * 2];
            float4 c01 = g4[clin0 * 16 + dq * 2 + 1];
            float4 c10 = g4[clin1 * 16 + dq * 2];
            float4 c11 = g4[clin1 * 16 + dq * 2 + 1];
            float4* w0 = (float4*)&coefL[0][g][dq * 8];
            w0[0] = c00; w0[1] = c01;
            float4* w1 = (float4*)&coefL[1][g][dq * 8];
            w1[0] = c10; w1[1] = c11;
        }
        // group lives inside one wave: LDS write->read ordering is program order

        float4 pr0[8], pr1[8];
        #pragma unroll
        for (int f = 0; f < 8; ++f) {
            pr0[f] = make_float4(0.f, 0.f, 0.f, 0.f);
            pr1[f] = make_float4(0.f, 0.f, 0.f, 0.f);
        }

        for (int a = 0; a < 64; ++a) {
            float c0 = coefL[0][g][a];
            float c1 = coefL[1][g][a];
            #pragma unroll
            for (int f = 0; f < 8; ++f) {
                float4 at = at4[(f * 64 + a) * 7 + dqe];
                pr0[f].x = fmaf(c0, at.x, pr0[f].x);
                pr0[f].y = fmaf(c0, at.y, pr0[f].y);
                pr0[f].z = fmaf(c0, at.z, pr0[f].z);
                pr0[f].w = fmaf(c0, at.w, pr0[f].w);
                pr1[f].x = fmaf(c1, at.x, pr1[f].x);
                pr1[f].y = fmaf(c1, at.y, pr1[f].y);
                pr1[f].z = fmaf(c1, at.z, pr1[f].z);
                pr1[f].w = fmaf(c1, at.w, pr1[f].w);
            }
        }

        float4 d0 = make_float4(0.f, 0.f, 0.f, 0.f);
        float4 d1 = make_float4(0.f, 0.f, 0.f, 0.f);
        #pragma unroll
        for (int f = 0; f < 8; ++f) {
            d0.x = fmaf(W0[f], pr0[f].x, d0.x);
            d0.y = fmaf(W0[f], pr0[f].y, d0.y);
            d0.z = fmaf(W0[f], pr0[f].z, d0.z);
            d0.w = fmaf(W0[f], pr0[f].w, d0.w);
            d1.x = fmaf(W1[f], pr1[f].x, d1.x);
            d1.y = fmaf(W1[f], pr1[f].y, d1.y);
            d1.z = fmaf(W1[f], pr1[f].z, d1.z);
            d1.w = fmaf(W1[f], pr1[f].w, d1.w);
        }

        emit(s0, d0, m0);
        emit(s1, d1, m1);
    }

    __syncthreads();

    // ---- phase 2: transmittance scan + composite (wave 0 only) ----
    if (tid < 64) {
        int sA = tid * 12;
        int sB = min(sA + 12, NSAMP);
        float prod = 1.f;
        for (int s = sA; s < sB; ++s)
            prod *= (1.f - __bfloat162float(alphaL[s]) + 1e-10f);

        float incl = prod;
        #pragma unroll
        for (int off = 1; off < 64; off <<= 1) {
            float v = __shfl_up(incl, off, 64);
            if (tid >= off) incl *= v;
        }
        float excl = __shfl_up(incl, 1, 64);
        if (tid == 0) excl = 1.f;

        float trans = excl;
        float c0 = 0.f, c1 = 0.f, c2 = 0.f, acc = 0.f, dep = 0.f;
        for (int s = sA; s < sB; ++s) {
            float a = __bfloat162float(alphaL[s]);
            float w = a * trans;
            c0 += w * __bfloat162float(rgbL[s * 3 + 0]);
            c1 += w * __bfloat162float(rgbL[s * 3 + 1]);
            c2 += w * __bfloat162float(rgbL[s * 3 + 2]);
            acc += w;
            dep += w * (start + (float)s * STEPF);
            trans *= (1.f - a + 1e-10f);
        }
        #pragma unroll
        for (int off = 1; off < 64; off <<= 1) {
            c0  += __shfl_xor(c0, off, 64);
            c1  += __shfl_xor(c1, off, 64);
            c2  += __shfl_xor(c2, off, 64);
            acc += __shfl_xor(acc, off, 64);
            dep += __shfl_xor(dep, off, 64);
        }
        if (tid == 0) {
            float bg = 1.f - acc;
            out_rgb[ray * 3 + 0] = c0 + bg;
            out_rgb[ray * 3 + 1] = c1 + bg;
            out_rgb[ray * 3 + 2] = c2 + bg;
            out_depth[ray] = dep;
        }
    }
}

extern "C" void kernel_launch(void* const* d_in, const int* in_sizes, int n_in,
                              void* d_out, int out_size, void* d_ws, size_t ws_size,
                              hipStream_t stream) {
    const float* rays_o = (const float*)d_in[0];
    const float* rays_d = (const float*)d_in[1];
    const float* grid   = (const float*)d_in[2];
    const float* atoms  = (const float*)d_in[3];
    float* out = (float*)d_out;
    hipLaunchKernelGGL(plenoxels_fwd, dim3(BATCH), dim3(256), 0, stream,
                       rays_o, rays_d, grid, atoms, out);
}

// Round 3
// 151.345 us; speedup vs baseline: 2.6257x; 2.6257x over previous
//
#include <hip/hip_runtime.h>
#include <hip/hip_bf16.h>

#define RADIUS_F 1.3f
#define NSAMP 767
#define STEPF 0.01015625f   // RADIUS*2/COARSE/FINE/2
#define BATCH 1024

typedef __attribute__((ext_vector_type(8))) short short8;
typedef __attribute__((ext_vector_type(4))) float floatx4;

static __device__ __forceinline__ unsigned pkbf(float a, float b) {
    union { __hip_bfloat162 h; unsigned u; } cvt;
    cvt.h = __float22bfloat162_rn(make_float2(a, b));
    return cvt.u;
}

__launch_bounds__(256, 2)
__global__ void plenoxels_fwd(const float* __restrict__ rays_o,
                              const float* __restrict__ rays_d,
                              const float* __restrict__ grid,
                              const float* __restrict__ atoms,
                              float* __restrict__ out)
{
    // LDS: 16640 (B') + 16384 (coef) + 1536 + 4608 = 39168 B
    __shared__ __align__(16) __hip_bfloat16 BpL[16 * 520];  // B'[n][k] bf16; rows 0-3 = r,g,b,sigma; 4-15 zero
    __shared__ __align__(16) float coefL[4 * 1024];         // per-wave coeff[16][64], XOR-swizzled 16B chunks
    __shared__ __align__(16) __hip_bfloat16 alphaL[768];
    __shared__ __align__(16) __hip_bfloat16 rgbL[768 * 3];

    const int tid  = threadIdx.x;
    const int ray  = blockIdx.x;
    const int lane = tid & 63;
    const int w    = tid >> 6;
    const int m    = lane & 15;   // A-frag row (sample-in-tile), B-frag col, C col
    const int quad = lane >> 4;

    // ---- per-ray constants (redundant per thread) ----
    const float ox = rays_o[ray * 3 + 0], oy = rays_o[ray * 3 + 1], oz = rays_o[ray * 3 + 2];
    const float dx = rays_d[ray * 3 + 0], dy = rays_d[ray * 3 + 1], dz = rays_d[ray * 3 + 2];

    float start;
    {
        float a0 = (RADIUS_F - ox) / dx, b0 = (-RADIUS_F - ox) / dx;
        float a1 = (RADIUS_F - oy) / dy, b1 = (-RADIUS_F - oy) / dy;
        float a2 = (RADIUS_F - oz) / dz, b2 = (-RADIUS_F - oz) / dz;
        start = fmaxf(fminf(a0, b0), fmaxf(fminf(a1, b1), fminf(a2, b2)));
    }
    const float dnorm = sqrtf(dx * dx + dy * dy + dz * dz);
    const float dist = STEPF * dnorm;

    float shm[9];
    {
        float inv = 1.0f / dnorm;
        float nx = dx * inv, ny = dy * inv, nz = dz * inv;
        shm[0] = 0.28209479177387814f;
        shm[1] = -0.4886025119029199f * ny;
        shm[2] = 0.4886025119029199f * nz;
        shm[3] = -0.4886025119029199f * nx;
        shm[4] = 1.0925484305920792f * nx * ny;
        shm[5] = -1.0925484305920792f * ny * nz;
        shm[6] = 0.31539156525252005f * (2.f * nz * nz - nx * nx - ny * ny);
        shm[7] = -1.0925484305920792f * nx * nz;
        shm[8] = 0.5462742152960396f * (nx * nx - ny * ny);
    }

    // ---- build B' = atoms-matrix pre-contracted with SH weights (per block) ----
    {
        unsigned* z = (unsigned*)BpL;
        for (int i = tid; i < (16 * 520) / 2; i += 256) z[i] = 0u;
    }
    __syncthreads();
    for (int k = tid; k < 512; k += 256) {
        int f = k & 7, a = k >> 3;                 // k = a*8 + f
        const float* base = atoms + (f * 64 + a) * 28;
        float s0 = 0.f, s1 = 0.f, s2 = 0.f;
        #pragma unroll
        for (int i = 0; i < 9; ++i) {
            s0 = fmaf(base[i],      shm[i], s0);
            s1 = fmaf(base[9 + i],  shm[i], s1);
            s2 = fmaf(base[18 + i], shm[i], s2);
        }
        BpL[0 * 520 + k] = __float2bfloat16(s0);
        BpL[1 * 520 + k] = __float2bfloat16(s1);
        BpL[2 * 520 + k] = __float2bfloat16(s2);
        BpL[3 * 520 + k] = __float2bfloat16(base[27]);   // sigma column
    }
    __syncthreads();

    // ---- load all 16 B'-fragments into registers (reused by all 12 tiles) ----
    short8 bfr[16];
    {
        const short* bs = (const short*)BpL;
        #pragma unroll
        for (int ks = 0; ks < 16; ++ks)
            bfr[ks] = *(const short8*)(bs + m * 520 + ks * 32 + quad * 8);
    }

    float* out_rgb   = out;
    float* out_alpha = out + BATCH * 3;
    float* out_depth = out + BATCH * 3 + BATCH * NSAMP;
    const float4* g4 = (const float4*)grid;
    float* coefW = coefL + (w << 10);

    // geometry + trilinear fine weights (same as round 1, verified)
    auto geom = [&](int s, float W[8], int& clin) -> int {
        float tr = start + (float)s * STEPF;
        float px = ox + tr * dx, py = oy + tr * dy, pz = oz + tr * dz;
        int mask = (px > -RADIUS_F) & (px < RADIUS_F) &
                   (py > -RADIUS_F) & (py < RADIUS_F) &
                   (pz > -RADIUS_F) & (pz < RADIUS_F);
        const float sc = 1.0f / (2.0f * RADIUS_F);
        float qx = fminf(fmaxf((px + RADIUS_F) * sc, 0.f), 1.0f - 1e-6f);
        float qy = fminf(fmaxf((py + RADIUS_F) * sc, 0.f), 1.0f - 1e-6f);
        float qz = fminf(fmaxf((pz + RADIUS_F) * sc, 0.f), 1.0f - 1e-6f);
        float pcx = qx * 64.f, pcy = qy * 64.f, pcz = qz * 64.f;
        float cx = fminf(floorf(pcx), 63.f);
        float cy = fminf(floorf(pcy), 63.f);
        float cz = fminf(floorf(pcz), 63.f);
        float lx = pcx - cx, ly = pcy - cy, lz = pcz - cz;
        clin = (((int)cx * 64) + (int)cy) * 64 + (int)cz;
        float xw0, xw1, yw0, yw1, zw0, zw1;
        {
            float u = lx * 2.f - 0.5f, fF = floorf(u), t = u - fF;
            xw0 = (fF < 0.f) ? 1.f : ((fF > 0.f) ? 0.f : 1.f - t);
            xw1 = (fF < 0.f) ? 0.f : ((fF > 0.f) ? 1.f : t);
        }
        {
            float u = ly * 2.f - 0.5f, fF = floorf(u), t = u - fF;
            yw0 = (fF < 0.f) ? 1.f : ((fF > 0.f) ? 0.f : 1.f - t);
            yw1 = (fF < 0.f) ? 0.f : ((fF > 0.f) ? 1.f : t);
        }
        {
            float u = lz * 2.f - 0.5f, fF = floorf(u), t = u - fF;
            zw0 = (fF < 0.f) ? 1.f : ((fF > 0.f) ? 0.f : 1.f - t);
            zw1 = (fF < 0.f) ? 0.f : ((fF > 0.f) ? 1.f : t);
        }
        W[0] = xw0 * yw0 * zw0; W[1] = xw0 * yw0 * zw1;
        W[2] = xw0 * yw1 * zw0; W[3] = xw0 * yw1 * zw1;
        W[4] = xw1 * yw0 * zw0; W[5] = xw1 * yw0 * zw1;
        W[6] = xw1 * yw1 * zw0; W[7] = xw1 * yw1 * zw1;
        return mask;
    };

    // ---- software-pipelined tile loop: 12 tiles x 16 samples per wave ----
    float Wc[8]; int clinC; int maskC;
    maskC = geom(w * 192 + m, Wc, clinC);
    float4 cA, cB, cC, cD;
    {
        const float4* gp = g4 + (clinC << 4) + (quad << 2);
        cA = gp[0]; cB = gp[1]; cC = gp[2]; cD = gp[3];
    }

    for (int t = 0; t < 12; ++t) {
        const int tile = w * 12 + t;

        // stage coeff rows: lane(m,quad) holds coeff[m][16q..16q+15]; XOR-swizzle 16B chunks by m
        {
            float* b0 = coefW + (m << 6);
            *(float4*)(b0 + ((((quad << 2) + 0) ^ m) << 2)) = cA;
            *(float4*)(b0 + ((((quad << 2) + 1) ^ m) << 2)) = cB;
            *(float4*)(b0 + ((((quad << 2) + 2) ^ m) << 2)) = cC;
            *(float4*)(b0 + ((((quad << 2) + 3) ^ m) << 2)) = cD;
        }
        float Wk[8];
        #pragma unroll
        for (int j = 0; j < 8; ++j) Wk[j] = Wc[j];
        const int maskS = maskC;

        // prefetch next tile's geometry + grid gather (hides L2 latency under MFMA loop)
        if (t < 11) {
            maskC = geom(w * 192 + (t + 1) * 16 + m, Wc, clinC);
            const float4* gp = g4 + (clinC << 4) + (quad << 2);
            cA = gp[0]; cB = gp[1]; cC = gp[2]; cD = gp[3];
        }

        // K-loop: A[m][k] = coeff[m][k>>3] * W[m][k&7], k = ks*32 + quad*8 + j
        floatx4 acc = {0.f, 0.f, 0.f, 0.f};
        #pragma unroll
        for (int ks = 0; ks < 16; ++ks) {
            float cr = coefW[(m << 6) + (((ks ^ m) & 15) << 2) + quad];  // coeff[m][4*ks+quad]
            union { unsigned u[4]; short8 s; } af;
            af.u[0] = pkbf(cr * Wk[0], cr * Wk[1]);
            af.u[1] = pkbf(cr * Wk[2], cr * Wk[3]);
            af.u[2] = pkbf(cr * Wk[4], cr * Wk[5]);
            af.u[3] = pkbf(cr * Wk[6], cr * Wk[7]);
            acc = __builtin_amdgcn_mfma_f32_16x16x32_bf16(af.s, bfr[ks], acc, 0, 0, 0);
        }

        // epilogue: C[row=quad*4+r][col=m]; col 0..2 = rgb channels, col 3 = sigma
        #pragma unroll
        for (int r = 0; r < 4; ++r) {
            int srow = (quad << 2) + r;
            int s = (tile << 4) + srow;
            int mk = __shfl(maskS, (lane & 48) + srow, 64);
            float v = acc[r];
            if (s < NSAMP) {
                if (m == 3) {
                    float sg = mk ? fmaxf(v, 0.f) : 0.f;
                    float al = 1.f - __expf(-sg * dist);
                    out_alpha[ray * NSAMP + s] = al;     // exact fp32 output
                    alphaL[s] = __float2bfloat16(al);
                } else if (m < 3) {
                    float rv = mk ? (1.f / (1.f + __expf(-v))) : 0.5f;
                    rgbL[s * 3 + m] = __float2bfloat16(rv);
                }
            }
        }
    }

    __syncthreads();

    // ---- phase 2: transmittance scan + composite (wave 0 only) ----
    if (tid < 64) {
        int sA = tid * 12;
        int sB = min(sA + 12, NSAMP);
        float prod = 1.f;
        for (int s = sA; s < sB; ++s)
            prod *= (1.f - __bfloat162float(alphaL[s]) + 1e-10f);

        float incl = prod;
        #pragma unroll
        for (int off = 1; off < 64; off <<= 1) {
            float v = __shfl_up(incl, off, 64);
            if (tid >= off) incl *= v;
        }
        float excl = __shfl_up(incl, 1, 64);
        if (tid == 0) excl = 1.f;

        float trans = excl;
        float c0 = 0.f, c1 = 0.f, c2 = 0.f, acc = 0.f, dep = 0.f;
        for (int s = sA; s < sB; ++s) {
            float a = __bfloat162float(alphaL[s]);
            float wgt = a * trans;
            c0 += wgt * __bfloat162float(rgbL[s * 3 + 0]);
            c1 += wgt * __bfloat162float(rgbL[s * 3 + 1]);
            c2 += wgt * __bfloat162float(rgbL[s * 3 + 2]);
            acc += wgt;
            dep += wgt * (start + (float)s * STEPF);
            trans *= (1.f - a + 1e-10f);
        }
        #pragma unroll
        for (int off = 1; off < 64; off <<= 1) {
            c0  += __shfl_xor(c0, off, 64);
            c1  += __shfl_xor(c1, off, 64);
            c2  += __shfl_xor(c2, off, 64);
            acc += __shfl_xor(acc, off, 64);
            dep += __shfl_xor(dep, off, 64);
        }
        if (tid == 0) {
            float bg = 1.f - acc;
            out_rgb[ray * 3 + 0] = c0 + bg;
            out_rgb[ray * 3 + 1] = c1 + bg;
            out_rgb[ray * 3 + 2] = c2 + bg;
            out_depth[ray] = dep;
        }
    }
}

extern "C" void kernel_launch(void* const* d_in, const int* in_sizes, int n_in,
                              void* d_out, int out_size, void* d_ws, size_t ws_size,
                              hipStream_t stream) {
    const float* rays_o = (const float*)d_in[0];
    const float* rays_d = (const float*)d_in[1];
    const float* grid   = (const float*)d_in[2];
    const float* atoms  = (const float*)d_in[3];
    float* out = (float*)d_out;
    hipLaunchKernelGGL(plenoxels_fwd, dim3(BATCH), dim3(256), 0, stream,
                       rays_o, rays_d, grid, atoms, out);
}